// Round 3
// baseline (115.356 us; speedup 1.0000x reference)
//
#include <hip/hip_runtime.h>
#include <hip/hip_bf16.h>

#define EPS 0.3f

typedef float vf4 __attribute__((ext_vector_type(4)));

__device__ __forceinline__ float eps_fix(float x) {
    return (fabsf(x) < EPS) ? ((x < 0.0f) ? -EPS : EPS) : x;
}

__device__ __forceinline__ vf4 eps_fix4(vf4 v) {
    vf4 r;
    r.x = eps_fix(v.x);
    r.y = eps_fix(v.y);
    r.z = eps_fix(v.z);
    r.w = eps_fix(v.w);
    return r;
}

__global__ void eps_clamp_kernel(const vf4* __restrict__ in,
                                 vf4* __restrict__ out,
                                 int n4) {
    int tid = blockIdx.x * blockDim.x + threadIdx.x;
    int stride = gridDim.x * blockDim.x;

    // 4-way unrolled grid-stride: issue 4 independent NT loads, then compute,
    // then 4 NT stores. 64 B in flight per thread per iteration.
    int i = tid;
    for (; i + 3 * stride < n4; i += 4 * stride) {
        vf4 v0 = __builtin_nontemporal_load(&in[i]);
        vf4 v1 = __builtin_nontemporal_load(&in[i + stride]);
        vf4 v2 = __builtin_nontemporal_load(&in[i + 2 * stride]);
        vf4 v3 = __builtin_nontemporal_load(&in[i + 3 * stride]);
        __builtin_nontemporal_store(eps_fix4(v0), &out[i]);
        __builtin_nontemporal_store(eps_fix4(v1), &out[i + stride]);
        __builtin_nontemporal_store(eps_fix4(v2), &out[i + 2 * stride]);
        __builtin_nontemporal_store(eps_fix4(v3), &out[i + 3 * stride]);
    }
    for (; i < n4; i += stride) {
        vf4 v = __builtin_nontemporal_load(&in[i]);
        __builtin_nontemporal_store(eps_fix4(v), &out[i]);
    }
}

extern "C" void kernel_launch(void* const* d_in, const int* in_sizes, int n_in,
                              void* d_out, int out_size, void* d_ws, size_t ws_size,
                              hipStream_t stream) {
    const float* x = (const float*)d_in[0];
    float* out = (float*)d_out;
    int n = in_sizes[0];          // 8192*8192 = 67108864, divisible by 4
    int n4 = n / 4;

    const int block = 256;
    int grid = (n4 + block - 1) / block;
    if (grid > 2048) grid = 2048;  // 256 CU × 8 blocks; grid-stride the rest

    eps_clamp_kernel<<<grid, block, 0, stream>>>(
        (const vf4*)x, (vf4*)out, n4);
}

// Round 4
// 93.416 us; speedup vs baseline: 1.2349x; 1.2349x over previous
//
#include <hip/hip_runtime.h>
#include <hip/hip_bf16.h>

#define EPS 0.3f

typedef float vf4 __attribute__((ext_vector_type(4)));

__device__ __forceinline__ float eps_fix(float x) {
    return (fabsf(x) < EPS) ? ((x < 0.0f) ? -EPS : EPS) : x;
}

__global__ void eps_clamp_kernel(const vf4* __restrict__ in,
                                 vf4* __restrict__ out,
                                 int n4) {
    int tid = blockIdx.x * blockDim.x + threadIdx.x;
    if (tid < n4) {
        vf4 v = in[tid];
        vf4 r;
        r.x = eps_fix(v.x);
        r.y = eps_fix(v.y);
        r.z = eps_fix(v.z);
        r.w = eps_fix(v.w);
        out[tid] = r;
    }
}

extern "C" void kernel_launch(void* const* d_in, const int* in_sizes, int n_in,
                              void* d_out, int out_size, void* d_ws, size_t ws_size,
                              hipStream_t stream) {
    const float* x = (const float*)d_in[0];
    float* out = (float*)d_out;
    int n = in_sizes[0];          // 8192*8192 = 67108864, divisible by 4
    int n4 = n / 4;

    const int block = 256;
    int grid = (n4 + block - 1) / block;   // 65536 blocks, one float4/thread

    eps_clamp_kernel<<<grid, block, 0, stream>>>(
        (const vf4*)x, (vf4*)out, n4);
}